// Round 5
// baseline (311.578 us; speedup 1.0000x reference)
//
#include <hip/hip_runtime.h>

typedef short bf16x8 __attribute__((ext_vector_type(8)));
typedef float f32x4 __attribute__((ext_vector_type(4)));
typedef float f32x16 __attribute__((ext_vector_type(16)));

__device__ __forceinline__ ushort f2bf(float f) {
    union { float f; unsigned u; } v; v.f = f;
    unsigned r = (v.u + 0x7fffu + ((v.u >> 16) & 1u)) >> 16;
    return (ushort)r;
}
__device__ __forceinline__ float bf2f(ushort u) {
    union { unsigned u; float f; } v; v.u = ((unsigned)u) << 16;
    return v.f;
}
__device__ __forceinline__ void async_copy16(void* lds, const void* g) {
    __builtin_amdgcn_global_load_lds(
        (const __attribute__((address_space(1))) unsigned*)g,
        (__attribute__((address_space(3))) unsigned*)lds, 16, 0, 0);
}

// ---------------- fp32 -> bf16 conversion ----------------
__global__ __launch_bounds__(256)
void cvt_f32_bf16(const float* __restrict__ src, ushort* __restrict__ dst, int n) {
    int i = (blockIdx.x * 256 + threadIdx.x) * 4;
    if (i >= n) return;
    float4 v = *(const float4*)(src + i);
    ushort4 o;
    o.x = f2bf(v.x); o.y = f2bf(v.y); o.z = f2bf(v.z); o.w = f2bf(v.w);
    *(ushort4*)(dst + i) = o;
}

// fused weight conversion: Wq|Wk|Wv (3 x 262144) -> contiguous bf16 stack
__global__ __launch_bounds__(256)
void cvt_w(const float* __restrict__ a, const float* __restrict__ b,
           const float* __restrict__ c, ushort* __restrict__ dst) {
    int i = (blockIdx.x * 256 + threadIdx.x) * 4;
    const float* src; int off;
    if (i < 262144)      { src = a; off = i; }
    else if (i < 524288) { src = b; off = i - 262144; }
    else                 { src = c; off = i - 524288; }
    float4 v = *(const float4*)(src + off);
    ushort4 o;
    o.x = f2bf(v.x); o.y = f2bf(v.y); o.z = f2bf(v.z); o.w = f2bf(v.w);
    *(ushort4*)(dst + i) = o;
}

// ---------------- C[m][n] = sum_k A[m][k] * B[n][k], bf16 in/out, fp32 acc ----
__global__ __launch_bounds__(256, 2)
void gemm_bt(const ushort* __restrict__ A, const ushort* __restrict__ B,
             ushort* __restrict__ C, int M, int N, int K)
{
    __shared__ ushort As[128][40];
    __shared__ ushort Bs[128][40];
    const int tid = threadIdx.x;
    const int lane = tid & 63, wave = tid >> 6;
    const int wm = wave >> 1, wn = wave & 1;
    const int lr = lane & 15, lq = lane >> 4;
    const int mBase = blockIdx.y * 128, nBase = blockIdx.x * 128;

    f32x4 acc[4][4];
    #pragma unroll
    for (int i = 0; i < 4; ++i)
        #pragma unroll
        for (int j = 0; j < 4; ++j) acc[i][j] = (f32x4){0.f, 0.f, 0.f, 0.f};

    for (int k0 = 0; k0 < K; k0 += 32) {
        __syncthreads();
        #pragma unroll
        for (int i = 0; i < 2; ++i) {
            int off = i * 4096 + tid * 16;
            int row = off >> 6, col = off & 63;
            *(uint4*)((char*)As + row * 80 + col) =
                *(const uint4*)((const char*)A + ((size_t)(mBase + row) * K + k0) * 2 + col);
            *(uint4*)((char*)Bs + row * 80 + col) =
                *(const uint4*)((const char*)B + ((size_t)(nBase + row) * K + k0) * 2 + col);
        }
        __syncthreads();
        bf16x8 af[4], bfr[4];
        #pragma unroll
        for (int mi = 0; mi < 4; ++mi) af[mi] = *(const bf16x8*)&As[wm * 64 + mi * 16 + lr][lq * 8];
        #pragma unroll
        for (int ni = 0; ni < 4; ++ni) bfr[ni] = *(const bf16x8*)&Bs[wn * 64 + ni * 16 + lr][lq * 8];
        #pragma unroll
        for (int mi = 0; mi < 4; ++mi)
            #pragma unroll
            for (int ni = 0; ni < 4; ++ni)
                acc[mi][ni] = __builtin_amdgcn_mfma_f32_16x16x32_bf16(af[mi], bfr[ni], acc[mi][ni], 0, 0, 0);
    }
    #pragma unroll
    for (int mi = 0; mi < 4; ++mi)
        #pragma unroll
        for (int ni = 0; ni < 4; ++ni)
            #pragma unroll
            for (int r = 0; r < 4; ++r) {
                int m = mBase + wm * 64 + mi * 16 + lq * 4 + r;
                int n = nBase + wn * 64 + ni * 16 + lr;
                C[(size_t)m * N + n] = f2bf(acc[mi][ni][r]);
            }
}

// ---------------- flash attention: split-S, static-max, pair-split PV, -------
// ---------------- 16-key tiles with DOUBLE-BUFFERED K DMA ---------------------
// QK: [B*S][1024] bf16 (col 0..511 = Q, 512..1023 = K). Vt: [512][B*S] bf16.
// Grid (32, 8, 2). Per iter (16 keys): issue DMA(kt+1) -> QK(kt) -> softmax
// -> Ps/Vs write -> B_mid (drains DMA with ~full QK phase in flight behind it)
// -> PV -> B_top(next). No barrier has an exposed long-latency drain.
__global__ __launch_bounds__(256, 2)
void attn_kernel(const ushort* __restrict__ QKg, const ushort* __restrict__ Vtg,
                 const int* __restrict__ maskg,
                 ushort* __restrict__ Pog, float* __restrict__ Mlg)
{
    const int S = 2048;
    const float SL2E = 0.0637587160f;  // (1/sqrt(512)) * log2(e)

    __shared__ ushort Ks[2][16][548]; // dbuf; stride 548 ush = 274 dw == 18 mod 32
    __shared__ ushort Vs[512][20];    // 512 d x 16 keys; stride 20 ush = 10 dw (2-way, free)
    __shared__ ushort Ps[2][32][20];  // per-pair P 32 rows x 16 keys

    const int b = blockIdx.y, qt = blockIdx.x, half = blockIdx.z;
    const int tid = threadIdx.x, lane = tid & 63, wave = tid >> 6;
    const int lr = lane & 15, lq = lane >> 4;
    const int p = wave >> 1, s = wave & 1;
    const int l32 = lane & 31, lh = lane >> 5;

    // resident Q fragments (QK row stride 1024 ush, Q at col 0)
    const ushort* Qp = QKg + ((size_t)b * S + qt * 64 + wave * 16 + lr) * 1024;
    bf16x8 qf[16];
    #pragma unroll
    for (int c = 0; c < 16; ++c) qf[c] = *(const bf16x8*)(Qp + c * 32 + lq * 8);

    f32x16 o[8];
    #pragma unroll
    for (int i = 0; i < 8; ++i)
        #pragma unroll
        for (int r = 0; r < 16; ++r) o[i][r] = 0.f;
    float l_i[4] = {0.f, 0.f, 0.f, 0.f};

    const char* Khalf = (const char*)(QKg + ((size_t)b * S + half * 1024) * 1024 + 512);
    const char* Vhalf = (const char*)Vtg + ((size_t)b * 2048 + half * 1024) * 2;
    const int* mrow = maskg + b * S + half * 1024;

    // prologue: DMA tile 0 into Ks[0] (4 rows per wave, one 1024B row per instr)
    #pragma unroll
    for (int i = 0; i < 4; ++i) {
        int row = wave * 4 + i;
        async_copy16(&Ks[0][row][0], Khalf + (size_t)row * 2048 + lane * 16);
    }

    for (int kt = 0; kt < 64; ++kt) {
        const int key0 = kt * 16;
        const int cur = kt & 1;
        __syncthreads();  // B_top: Ks[cur] ready (drained last B_mid / prologue);
                          //        Vs,Ps writable (PV(kt-1) done)
        // issue DMA for tile kt+1 into Ks[cur^1] — in flight behind QK+softmax
        if (kt < 63) {
            const char* gK = Khalf + (size_t)(key0 + 16) * 2048;
            #pragma unroll
            for (int i = 0; i < 4; ++i) {
                int row = wave * 4 + i;
                async_copy16(&Ks[cur ^ 1][row][0], gK + (size_t)row * 2048 + lane * 16);
            }
        }
        // V tile prefetch into regs (consumed at Vs write below)
        uint4 vreg[4];
        {
            const char* gV = Vhalf + (size_t)key0 * 2;
            #pragma unroll
            for (int i = 0; i < 4; ++i) {
                int off = i * 4096 + tid * 16;
                int row = off >> 5, col = off & 31;
                vreg[i] = *(const uint4*)(gV + (size_t)row * 32768 + col);
            }
        }
        const bool msk = mrow[key0 + lr] != 0;
        // S = Q Ktile^T (16 keys): 16 mfma 16x16x32
        f32x4 sf = (f32x4){0.f, 0.f, 0.f, 0.f};
        #pragma unroll
        for (int ks = 0; ks < 16; ++ks) {
            bf16x8 kf = *(const bf16x8*)&Ks[cur][lr][ks * 32 + lq * 8];
            sf = __builtin_amdgcn_mfma_f32_16x16x32_bf16(qf[ks], kf, sf, 0, 0, 0);
        }
        // static-max softmax: p = exp2(score*SL2E - 8); l lane-local
        #pragma unroll
        for (int r = 0; r < 4; ++r) {
            float pr = msk ? 0.f : exp2f(fmaf(sf[r], SL2E, -8.f));
            l_i[r] += pr;
            Ps[p][16 * s + lq * 4 + r][lr] = f2bf(pr);
        }
        // V regs -> LDS
        #pragma unroll
        for (int i = 0; i < 4; ++i) {
            int off = i * 4096 + tid * 16;
            int row = off >> 5, col = off & 31;
            *(uint4*)((char*)Vs + row * 40 + col) = vreg[i];
        }
        __syncthreads();  // B_mid: Ps+Vs visible; drains DMA(kt+1) (covered by QK)
        // O += P(32x16) @ V(16 x d256) via mfma 32x32x16, d-range by s
        bf16x8 pA = *(const bf16x8*)&Ps[p][l32][lh * 8];
        #pragma unroll
        for (int dt = 0; dt < 8; ++dt) {
            int d = s * 256 + dt * 32 + l32;
            bf16x8 v = *(const bf16x8*)&Vs[d][lh * 8];
            o[dt] = __builtin_amdgcn_mfma_f32_32x32x16_bf16(pA, v, o[dt], 0, 0, 0);
        }
    }
    // final cross-lane l reduction (QK-wave owns rows 16w..16w+16)
    #pragma unroll
    for (int r = 0; r < 4; ++r)
        #pragma unroll
        for (int off = 1; off < 16; off <<= 1)
            l_i[r] += __shfl_xor(l_i[r], off, 16);
    const size_t growbase = (size_t)half * 16384 + (size_t)b * S + qt * 64;
    if (lr == 0) {
        #pragma unroll
        for (int r = 0; r < 4; ++r)
            Mlg[growbase + wave * 16 + lq * 4 + r] = l_i[r];
    }
    // write unnormalized partial O: pair rows [32p,32p+32), cols [256s,256s+256)
    // 32x32 C-layout: col = lane&31, row = (r&3) + 8*(r>>2) + 4*(lane>>5)
    ushort* Pop = Pog + (growbase + p * 32) * 512;
    #pragma unroll
    for (int dt = 0; dt < 8; ++dt) {
        int ocol = s * 256 + dt * 32 + l32;
        #pragma unroll
        for (int r = 0; r < 16; ++r) {
            int orow = (r & 3) + 8 * (r >> 2) + 4 * lh;
            Pop[(size_t)orow * 512 + ocol] = f2bf(o[dt][r]);
        }
    }
}

// ---------------- combine the two key-halves (shared static max) -------------
__global__ __launch_bounds__(256)
void combine_kernel(const ushort* __restrict__ Po, const float* __restrict__ Ml,
                    float* __restrict__ out)
{
    int i = (blockIdx.x * 256 + threadIdx.x) * 4;
    int row = i >> 9;
    float l = Ml[row] + Ml[16384 + row];
    float s = l > 0.f ? 1.f / l : 0.f;
    ushort4 p1 = *(const ushort4*)(Po + i);
    ushort4 p2 = *(const ushort4*)(Po + 8388608 + i);
    float4 o;
    o.x = (bf2f(p1.x) + bf2f(p2.x)) * s;
    o.y = (bf2f(p1.y) + bf2f(p2.y)) * s;
    o.z = (bf2f(p1.z) + bf2f(p2.z)) * s;
    o.w = (bf2f(p1.w) + bf2f(p2.w)) * s;
    *(float4*)(out + i) = o;
}

extern "C" void kernel_launch(void* const* d_in, const int* in_sizes, int n_in,
                              void* d_out, int out_size, void* d_ws, size_t ws_size,
                              hipStream_t stream) {
    const float* x  = (const float*)d_in[0];
    // d_in[1] = bias: additive scalar on all logits -> softmax shift-invariant -> no-op
    const int* mask = (const int*)d_in[2];
    const float* Wq = (const float*)d_in[3];
    const float* Wk = (const float*)d_in[4];
    const float* Wv = (const float*)d_in[5];
    float* out = (float*)d_out;

    // Workspace (ushort units). Region [0, 16777216) time-shared:
    //   phase 1: xb (8388608) + W-stack wq|wk|wv (786432)
    //   phase 2: Po (2 x 8388608 bf16 partial O)
    ushort* ws  = (ushort*)d_ws;
    ushort* xb  = ws;
    ushort* wst = ws + 8388608;            // Wq|Wk|Wv stacked (1536 x 512)
    ushort* Pob = ws;
    ushort* QKb = ws + 16777216;           // 16384 x 1024  ([Q|K] per row)
    ushort* Vtb = ws + 33554432;           // 512 x 16384   (V transposed)
    float*  Mlb = (float*)(ws + 41943040); // 32768 floats

    cvt_f32_bf16<<<8192, 256, 0, stream>>>(x, xb, 8388608);
    cvt_w<<<768, 256, 0, stream>>>(Wq, Wk, Wv, wst);
    // [Q|K] = x [Wq;Wk]^T  (M=16384, N=1024, K=512)
    gemm_bt<<<dim3(8, 128), 256, 0, stream>>>(xb, wst, QKb, 16384, 1024, 512);
    // Vt = Wv x^T  (M=512, N=16384, K=512)
    gemm_bt<<<dim3(128, 4), 256, 0, stream>>>(wst + 524288, xb, Vtb, 512, 16384, 512);
    attn_kernel<<<dim3(32, 8, 2), 256, 0, stream>>>(QKb, Vtb, mask, Pob, Mlb);
    combine_kernel<<<8192, 256, 0, stream>>>(Pob, Mlb, out);
}